// Round 2
// baseline (764.850 us; speedup 1.0000x reference)
//
#include <hip/hip_runtime.h>
#include <math.h>

// Problem constants: T=1024, B=8, H=8, N=32. D = H*N*N = 8192.
#define T_STEPS     1024
#define NBH         64            // B*H
#define NCHUNK      64            // 16-t chunks per bh
#define NREC        (NBH * NCHUNK)
#define REC_F       1088          // floats per record: kn[32][16] + vv[32][16] + bb[16] + pad(48)
#define SCAN_BLOCKS 128
#define STATS_BLOCKS 1024
#define SPIN_BOUND  (1 << 20)     // ~50 ms worst case; normal waits are us-scale

static __device__ __forceinline__ float fast_rcp(float x) {
  return __builtin_amdgcn_rcpf(x);
}
static __device__ __forceinline__ float fast_sigmoid(float x) {
  return fast_rcp(1.0f + __expf(-x));
}
// tanh(x) where y = 2x is passed: tanh = 1 - 2/(1+e^{2x})
static __device__ __forceinline__ float fast_tanh2(float y) {
  return 1.0f - 2.0f * fast_rcp(1.0f + __expf(y));
}

// DPP add: x + lane-permuted(x). CTRL is a compile-time DPP control.
template <int CTRL>
static __device__ __forceinline__ float dpp_add(float x) {
  int y = __builtin_amdgcn_update_dpp(0, __float_as_int(x), CTRL, 0xF, 0xF, true);
  return x + __int_as_float(y);
}

// Butterfly sum over each 16-lane group; result in all 16 lanes. Pure DPP.
static __device__ __forceinline__ float red16(float x) {
  x = dpp_add<0xB1>(x);    // quad_perm(1,0,3,2)  == xor 1
  x = dpp_add<0x4E>(x);    // quad_perm(2,3,0,1)  == xor 2
  x = dpp_add<0x141>(x);   // row_half_mirror     == xor 4
  x = dpp_add<0x140>(x);   // row_mirror          == xor 8
  return x;
}

// Zero the publish flags (graph-capture-safe replacement for hipMemsetAsync).
__global__ __launch_bounds__(256) void init_flags(int* __restrict__ flags) {
  const int gid = blockIdx.x * 256 + threadIdx.x;
  if (gid < NREC) flags[gid] = 0;
}

// ---------------------------------------------------------------------------
// Fused producer/consumer kernel.
//   blocks [0, 128)        : scan consumers (4 waves, 4 chains each; math
//                            identical to the verified R-series scan kernel)
//   blocks [128, 1152)     : stats producers, chunk-major (all bh of chunk c
//                            before chunk c+1), one wave per (bh, 16-t chunk)
// Producer publishes a contiguous 4352-B record per (bh,chunk) then sets a
// device-scope flag (release). Consumer acquire-fences before each chunk.
// Deadlock-free: producers wait on nothing; 128 consumer blocks can never
// occupy all 256 CUs, so producers always have slots. Spin is bounded as
// pure insurance: a visibility failure completes (wrong) instead of hanging.
// ---------------------------------------------------------------------------
__global__ __launch_bounds__(256, 1) void fused_kernel(
    const float* __restrict__ x, const float* __restrict__ S0,
    const float* __restrict__ scale_p, const float* __restrict__ bias_p,
    float* __restrict__ recs, int* __restrict__ flags,
    float* __restrict__ out, float* __restrict__ Sfin) {
  const int tid = threadIdx.x;

  if (blockIdx.x >= SCAN_BLOCKS) {
    // =============================== producer ===============================
    const int l   = tid & 63;
    const int m   = l & 7;
    const int g   = l >> 3;
    const int wib = tid >> 6;                       // wave in block 0..3
    const int job = (blockIdx.x - SCAN_BLOCKS) * 4 + wib;  // 0..4095
    const int bh  = job & 63;                       // chunk-major order!
    const int ch  = job >> 6;                       // 0..63
    const float sc = scale_p[0], bi = bias_p[0];

    __shared__ float kn_s[4][512];                  // [wave][elem*16 + tt]
    __shared__ float vv_s[4][512];
    __shared__ float bb_s[4][16];
    float* ks = kn_s[wib];
    float* vs = vv_s[wib];
    float* bs = bb_s[wib];

    // tile tt lives at x + ((16*ch+tt)*64 + bh)*1024 ; stride = 16384 float4
    const float4* xp = (const float4*)(x + (((size_t)ch * 16) * 64 + bh) * 1024);
    // 2-deep prefetch (co-residency with scan lowers waves/CU vs standalone
    // stats kernel; deeper prefetch keeps enough bytes in flight).
    float4 a0 = xp[l], a1 = xp[l + 64], a2 = xp[l + 128], a3 = xp[l + 192];
    const float4* x1 = xp + 16384;
    float4 b0 = x1[l], b1 = x1[l + 64], b2 = x1[l + 128], b3 = x1[l + 192];

#pragma unroll
    for (int tt = 0; tt < 16; ++tt) {
      float4 n0 = a0, n1 = a1, n2 = a2, n3 = a3;    // dead init (DCE'd)
      if (tt < 14) {
        const float4* xn = xp + (size_t)(tt + 2) * 16384;
        n0 = xn[l]; n1 = xn[l + 64]; n2 = xn[l + 128]; n3 = xn[l + 192];
      }

      // row partials; reduce over m: xor 1,2,4
      float r0 = (a0.x + a0.y) + (a0.z + a0.w);
      float r1 = (a1.x + a1.y) + (a1.z + a1.w);
      float r2 = (a2.x + a2.y) + (a2.z + a2.w);
      float r3 = (a3.x + a3.y) + (a3.z + a3.w);
      r0 += __shfl_xor(r0, 1); r1 += __shfl_xor(r1, 1);
      r2 += __shfl_xor(r2, 1); r3 += __shfl_xor(r3, 1);
      r0 += __shfl_xor(r0, 2); r1 += __shfl_xor(r1, 2);
      r2 += __shfl_xor(r2, 2); r3 += __shfl_xor(r3, 2);
      r0 += __shfl_xor(r0, 4); r1 += __shfl_xor(r1, 4);
      r2 += __shfl_xor(r2, 4); r3 += __shfl_xor(r3, 4);
      // r0..r3 = row sums for rows g, g+8, g+16, g+24 (all lanes)

      // col partials; reduce over g: xor 8,16,32
      float c0 = a0.x + a1.x + a2.x + a3.x;
      float c1 = a0.y + a1.y + a2.y + a3.y;
      float c2 = a0.z + a1.z + a2.z + a3.z;
      float c3 = a0.w + a1.w + a2.w + a3.w;
      c0 += __shfl_xor(c0, 8);  c1 += __shfl_xor(c1, 8);
      c2 += __shfl_xor(c2, 8);  c3 += __shfl_xor(c3, 8);
      c0 += __shfl_xor(c0, 16); c1 += __shfl_xor(c1, 16);
      c2 += __shfl_xor(c2, 16); c3 += __shfl_xor(c3, 16);
      c0 += __shfl_xor(c0, 32); c1 += __shfl_xor(c1, 32);
      c2 += __shfl_xor(c2, 32); c3 += __shfl_xor(c3, 32);
      // c0..c3 = col sums for cols 4m..4m+3 (all lanes)

      // sum(k), ||k||^2 over rows; reduce over g
      float t1 = (r0 + r1) + (r2 + r3);
      float t2 = (r0 * r0 + r1 * r1) + (r2 * r2 + r3 * r3);
      t1 += __shfl_xor(t1, 8);  t2 += __shfl_xor(t2, 8);
      t1 += __shfl_xor(t1, 16); t2 += __shfl_xor(t2, 16);
      t1 += __shfl_xor(t1, 32); t2 += __shfl_xor(t2, 32);
      const float norm = sqrtf(t2) * (1.0f / 32.0f);   // ||k||, k = rowsum/32
      const float kscl = (1.0f / 32.0f) * fast_rcp(norm + 1e-6f);

      if (m == 0) {          // 8 lanes: knorm elements g+8p for this tt
        ks[(g)      * 16 + tt] = r0 * kscl;
        ks[(g + 8)  * 16 + tt] = r1 * kscl;
        ks[(g + 16) * 16 + tt] = r2 * kscl;
        ks[(g + 24) * 16 + tt] = r3 * kscl;
      }
      if (l < 8) {           // lanes 0..7 (m==l): V2 = 2*colmean = colsum/16
        vs[(4 * m)     * 16 + tt] = c0 * (1.0f / 16.0f);
        vs[(4 * m + 1) * 16 + tt] = c1 * (1.0f / 16.0f);
        vs[(4 * m + 2) * 16 + tt] = c2 * (1.0f / 16.0f);
        vs[(4 * m + 3) * 16 + tt] = c3 * (1.0f / 16.0f);
      }
      if (l == 0) {          // B2 = 2*beta
        const float mean = t1 * (1.0f / 1024.0f);
        bs[tt] = 2.0f * fast_sigmoid(sc * mean + bi);
      }

      a0 = b0; a1 = b1; a2 = b2; a3 = b3;
      b0 = n0; b1 = n1; b2 = n2; b3 = n3;
    }

    // flush to the contiguous record (same wave wrote the LDS; lgkmcnt only)
    float* rec = recs + ((size_t)bh * NCHUNK + ch) * REC_F;
#pragma unroll
    for (int rep = 0; rep < 2; ++rep) {
      const int cc = l + rep * 64;                  // 0..127 -> float4 index
      *(float4*)(rec + 4 * cc)       = *(const float4*)&ks[4 * cc];
      *(float4*)(rec + 512 + 4 * cc) = *(const float4*)&vs[4 * cc];
    }
    if (l < 4) *(float4*)(rec + 1024 + 4 * l) = *(const float4*)&bs[4 * l];

    // publish: make record visible at agent scope, then set flag
    __builtin_amdgcn_fence(__ATOMIC_RELEASE, "agent");
    if (l == 0)
      __hip_atomic_store(&flags[bh * NCHUNK + ch], 1, __ATOMIC_RELAXED,
                         __HIP_MEMORY_SCOPE_AGENT);
    return;
  }

  // ================================ consumer ================================
  const int lane = tid & 63;
  const int g    = lane >> 4;                    // group in wave (0..3)
  const int s    = lane & 15;                    // lane in group
  const int w    = blockIdx.x * 4 + (tid >> 6);  // global wave 0..511
  const int bh   = w >> 3;                       // 0..63
  const int i    = (w & 7) * 4 + g;              // 0..31
  const int chain = bh * 32 + i;

  const float2 sini = *(const float2*)(S0 + (size_t)bh * 1024 + i * 32 + 2 * s);
  float Sa = sini.x, Sb = sini.y;

  const float* recb = recs + (size_t)bh * NCHUNK * REC_F;
  const int*   flg  = flags + bh * NCHUNK;
  float* outp = out + chain;

  float Ak0[16], Ak1[16], Av[16], Ab[16];
  float Bk0[16], Bk1[16], Bv[16], Bb[16];

#define FLAG_LD(c) \
  __hip_atomic_load(&flg[(c)], __ATOMIC_RELAXED, __HIP_MEMORY_SCOPE_AGENT)

// Spin (with prefetched first probe) until chunk c is published, then
// acquire-fence so its data reads are coherent. Spin is bounded purely as
// hang insurance (normal waits are us-scale; bound is ~50 ms).
#define WAITCHUNK(fv, c)                                                  \
  do {                                                                    \
    int _f = (fv);                                                        \
    int _n = 0;                                                           \
    while (_f == 0 && _n < SPIN_BOUND) {                                  \
      __builtin_amdgcn_s_sleep(2);                                        \
      _f = FLAG_LD(c);                                                    \
      ++_n;                                                               \
    }                                                                     \
    __builtin_amdgcn_fence(__ATOMIC_ACQUIRE, "agent");                    \
  } while (0)

#define LOAD_REC(K0, K1, VV, BE, CHK)                                     \
  do {                                                                    \
    const float* _r  = recb + (size_t)(CHK) * REC_F;                      \
    const float* _k0 = _r + (2 * s) * 16;                                 \
    const float* _k1 = _r + (2 * s + 1) * 16;                             \
    const float* _v  = _r + 512 + i * 16;                                 \
    const float* _b  = _r + 1024;                                         \
    _Pragma("unroll")                                                     \
    for (int qq = 0; qq < 4; ++qq) {                                      \
      *(float4*)&K0[4 * qq] = *(const float4*)(_k0 + 4 * qq);             \
      *(float4*)&K1[4 * qq] = *(const float4*)(_k1 + 4 * qq);             \
      *(float4*)&VV[4 * qq] = *(const float4*)(_v  + 4 * qq);             \
      *(float4*)&BE[4 * qq] = *(const float4*)(_b  + 4 * qq);             \
    }                                                                     \
  } while (0)

#define STEP_BLK(K0, K1, VV, BE, TBASE)                                   \
  do {                                                                    \
    float oacc = 0.0f;                                                    \
    _Pragma("unroll")                                                     \
    for (int u = 0; u < 16; ++u) {                                        \
      const float c0 = K0[u], c1 = K1[u];                                 \
      const float r  = red16(Sa * c0 + Sb * c1);                          \
      const float D2 = fmaf(-2.0f, r, VV[u]);   /* 2*(v - r) */           \
      const float B2 = BE[u];                                             \
      Sa = fast_tanh2(fmaf(B2, Sa, D2 * c0));                             \
      Sb = fast_tanh2(fmaf(B2, Sb, D2 * c1));                             \
      const float qv = red16(Sa * c0 + Sb * c1);                          \
      const float o  = qv * qv * fast_sigmoid(qv);                        \
      oacc = (u == s) ? o : oacc;                                         \
    }                                                                     \
    outp[(size_t)((TBASE) + s) * 2048] = oacc;                            \
  } while (0)

  int f0 = FLAG_LD(0);
  WAITCHUNK(f0, 0);
  LOAD_REC(Ak0, Ak1, Av, Ab, 0);                 // chunk 0 (t = 0..15)
  int fB = FLAG_LD(1);

  for (int c0 = 0; c0 < NCHUNK; c0 += 2) {
    const int cB  = c0 + 1;                      // always < NCHUNK
    const int cA2 = (c0 + 2 < NCHUNK) ? c0 + 2 : c0;  // clamp (dead data)
    WAITCHUNK(fB, cB);
    LOAD_REC(Bk0, Bk1, Bv, Bb, cB);              // prefetch block B
    int fA = FLAG_LD(cA2);                       // flag probe hidden under A
    STEP_BLK(Ak0, Ak1, Av, Ab, c0 * 16);         // compute block A
    WAITCHUNK(fA, cA2);
    LOAD_REC(Ak0, Ak1, Av, Ab, cA2);             // prefetch next block A
    fB = FLAG_LD((cB + 2 < NCHUNK) ? cB + 2 : cB);  // hidden under B
    STEP_BLK(Bk0, Bk1, Bv, Bb, cB * 16);         // compute block B
  }

#undef STEP_BLK
#undef LOAD_REC
#undef WAITCHUNK
#undef FLAG_LD

  float2 sfin; sfin.x = Sa; sfin.y = Sb;
  *(float2*)(Sfin + (size_t)bh * 1024 + i * 32 + 2 * s) = sfin;
}

extern "C" void kernel_launch(void* const* d_in, const int* in_sizes, int n_in,
                              void* d_out, int out_size, void* d_ws, size_t ws_size,
                              hipStream_t stream) {
  const float* x     = (const float*)d_in[0];   // [1024, 8, 8192] f32
  const float* S0    = (const float*)d_in[1];   // [8, 8, 32, 32] f32
  const float* scale = (const float*)d_in[2];   // scalar
  const float* bias  = (const float*)d_in[3];   // scalar
  float* out = (float*)d_out;                   // [1024,8,256] then S_final

  float* recs = (float*)d_ws;                   // [4096][1088] f32 (~17.8 MB)
  int* flags  = (int*)(recs + (size_t)NREC * REC_F);  // [4096] i32 (16 KB)

  // flags must start at 0 every replay (ws is poisoned between iterations);
  // tiny init kernel instead of hipMemsetAsync to stay graph-capture-safe.
  init_flags<<<16, 256, 0, stream>>>(flags);

  float* Sfin = out + (size_t)T_STEPS * 2048;   // after 2,097,152 output floats
  fused_kernel<<<SCAN_BLOCKS + STATS_BLOCKS, 256, 0, stream>>>(
      x, S0, scale, bias, recs, flags, out, Sfin);
}

// Round 4
// 634.765 us; speedup vs baseline: 1.2049x; 1.2049x over previous
//
#include <hip/hip_runtime.h>
#include <math.h>

// Problem constants: T=1024, B=8, H=8, N=32. D = H*N*N = 8192.
#define T_STEPS     1024
#define NBH         64            // B*H
#define NCHUNK      64            // 16-t chunks per bh
#define NREC        (NBH * NCHUNK)
#define REC_F       1088          // floats per record: kn[32][16] + vv[32][16] + bb[16] + pad
#define SCAN_BLOCKS 128
#define PROD_BLOCKS 128           // persistent producers: 128 blk x 4 waves x 8 jobs = 4096
#define SPIN_BOUND  (1 << 20)     // hang insurance only; normal waits are us-scale

static __device__ __forceinline__ float fast_rcp(float x) {
  return __builtin_amdgcn_rcpf(x);
}
static __device__ __forceinline__ float fast_sigmoid(float x) {
  return fast_rcp(1.0f + __expf(-x));
}
// tanh(x) where y = 2x is passed: tanh = 1 - 2/(1+e^{2x})
static __device__ __forceinline__ float fast_tanh2(float y) {
  return 1.0f - 2.0f * fast_rcp(1.0f + __expf(y));
}

// DPP add: x + lane-permuted(x). CTRL is a compile-time DPP control.
template <int CTRL>
static __device__ __forceinline__ float dpp_add(float x) {
  int y = __builtin_amdgcn_update_dpp(0, __float_as_int(x), CTRL, 0xF, 0xF, true);
  return x + __int_as_float(y);
}

// Butterfly sum over each 16-lane group; result in all 16 lanes. Pure DPP.
static __device__ __forceinline__ float red16(float x) {
  x = dpp_add<0xB1>(x);    // quad_perm(1,0,3,2)  == xor 1
  x = dpp_add<0x4E>(x);    // quad_perm(2,3,0,1)  == xor 2
  x = dpp_add<0x141>(x);   // row_half_mirror     == xor 4
  x = dpp_add<0x140>(x);   // row_mirror          == xor 8
  return x;
}

// One scan step (math byte-identical to the verified R-series scan kernel).
static __device__ __forceinline__ void step1(float& Sa, float& Sb, float k0,
                                             float k1, float vv, float b2,
                                             int u, int s, float& oacc) {
  const float r  = red16(Sa * k0 + Sb * k1);
  const float D2 = fmaf(-2.0f, r, vv);       /* 2*(v - r) */
  Sa = fast_tanh2(fmaf(b2, Sa, D2 * k0));
  Sb = fast_tanh2(fmaf(b2, Sb, D2 * k1));
  const float qv = red16(Sa * k0 + Sb * k1);
  const float o  = qv * qv * fast_sigmoid(qv);
  oacc = (u == s) ? o : oacc;
}

// Zero the publish flags (graph-capture-safe; ws is poisoned between replays).
__global__ __launch_bounds__(256) void init_flags(int* __restrict__ flags) {
  const int gid = blockIdx.x * 256 + threadIdx.x;
  if (gid < NREC) flags[gid] = 0;
}

// ---------------------------------------------------------------------------
// Fused producer/consumer kernel, 256 blocks total (~1 block/CU):
//   blocks [0, 128)    : scan consumers. ALL per-chunk state in named float4
//                        quads (no indexable arrays -> no scratch spill).
//   blocks [128, 256)  : persistent stats producers. Each wave: fixed bh,
//                        8 jobs (chunks c0base, c0base+8, ...), depth-4 tile
//                        prefetch pipeline. Chunk-major publication order.
// Producer publishes a contiguous 4352-B record then release-fence + flag.
// Consumer spins (bounded) on flags, one acquire fence per 2 chunks.
// Deadlock-free: producers wait on nothing; all 256 blocks are co-resident.
// ---------------------------------------------------------------------------
__global__ __launch_bounds__(256, 1) void fused_kernel(
    const float* __restrict__ x, const float* __restrict__ S0,
    const float* __restrict__ scale_p, const float* __restrict__ bias_p,
    float* __restrict__ recs, int* __restrict__ flags,
    float* __restrict__ out, float* __restrict__ Sfin) {
  const int tid = threadIdx.x;

  __shared__ float kn_s[4][512];                  // [wave][elem*16 + tt]
  __shared__ float vv_s[4][512];
  __shared__ float bb_s[4][16];

  if (blockIdx.x >= SCAN_BLOCKS) {
    // =============================== producer ===============================
    const int l    = tid & 63;
    const int m    = l & 7;
    const int g    = l >> 3;
    const int wib  = tid >> 6;                        // wave in block 0..3
    const int widx = (blockIdx.x - SCAN_BLOCKS) * 4 + wib;  // 0..511
    const int bh   = widx & 63;                       // fixed per wave
    const int c0b  = widx >> 6;                       // 0..7
    const int c016 = c0b * 16;
    const float sc = scale_p[0], bi = bias_p[0];

    float* ks = kn_s[wib];
    float* vs = vv_s[wib];
    float* bs = bb_s[wib];

    const float4* x4 = (const float4*)x;

    // tile stream index t (0..127): it = t>>4 (job), tt = t&15.
    // chunk ch = it*8 + c0b ; global tile gt = ch*16 + tt = it*128 + c016 + tt
    // float4 base of tile = gt*16384 + bh*256
#define LOAD_T(P, t)                                                      \
  do {                                                                    \
    const int _t  = (t);                                                  \
    const int _gt = ((_t) >> 4) * 128 + c016 + ((_t) & 15);               \
    const float4* _p = x4 + (size_t)_gt * 16384 + (size_t)bh * 256;       \
    P##t0 = _p[l];       P##t1 = _p[l + 64];                              \
    P##t2 = _p[l + 128]; P##t3 = _p[l + 192];                             \
  } while (0)

#define STAT_TILE(P, TT)                                                  \
  do {                                                                    \
    const int tt = (TT);                                                  \
    float r0 = (P##t0.x + P##t0.y) + (P##t0.z + P##t0.w);                 \
    float r1 = (P##t1.x + P##t1.y) + (P##t1.z + P##t1.w);                 \
    float r2 = (P##t2.x + P##t2.y) + (P##t2.z + P##t2.w);                 \
    float r3 = (P##t3.x + P##t3.y) + (P##t3.z + P##t3.w);                 \
    r0 += __shfl_xor(r0, 1); r1 += __shfl_xor(r1, 1);                     \
    r2 += __shfl_xor(r2, 1); r3 += __shfl_xor(r3, 1);                     \
    r0 += __shfl_xor(r0, 2); r1 += __shfl_xor(r1, 2);                     \
    r2 += __shfl_xor(r2, 2); r3 += __shfl_xor(r3, 2);                     \
    r0 += __shfl_xor(r0, 4); r1 += __shfl_xor(r1, 4);                     \
    r2 += __shfl_xor(r2, 4); r3 += __shfl_xor(r3, 4);                     \
    float c0 = P##t0.x + P##t1.x + P##t2.x + P##t3.x;                     \
    float c1 = P##t0.y + P##t1.y + P##t2.y + P##t3.y;                     \
    float c2 = P##t0.z + P##t1.z + P##t2.z + P##t3.z;                     \
    float c3 = P##t0.w + P##t1.w + P##t2.w + P##t3.w;                     \
    c0 += __shfl_xor(c0, 8);  c1 += __shfl_xor(c1, 8);                    \
    c2 += __shfl_xor(c2, 8);  c3 += __shfl_xor(c3, 8);                    \
    c0 += __shfl_xor(c0, 16); c1 += __shfl_xor(c1, 16);                   \
    c2 += __shfl_xor(c2, 16); c3 += __shfl_xor(c3, 16);                   \
    c0 += __shfl_xor(c0, 32); c1 += __shfl_xor(c1, 32);                   \
    c2 += __shfl_xor(c2, 32); c3 += __shfl_xor(c3, 32);                   \
    float t1 = (r0 + r1) + (r2 + r3);                                     \
    float t2 = (r0 * r0 + r1 * r1) + (r2 * r2 + r3 * r3);                 \
    t1 += __shfl_xor(t1, 8);  t2 += __shfl_xor(t2, 8);                    \
    t1 += __shfl_xor(t1, 16); t2 += __shfl_xor(t2, 16);                   \
    t1 += __shfl_xor(t1, 32); t2 += __shfl_xor(t2, 32);                   \
    const float norm = sqrtf(t2) * (1.0f / 32.0f);                        \
    const float kscl = (1.0f / 32.0f) * fast_rcp(norm + 1e-6f);           \
    if (m == 0) {                                                         \
      ks[(g)      * 16 + tt] = r0 * kscl;                                 \
      ks[(g + 8)  * 16 + tt] = r1 * kscl;                                 \
      ks[(g + 16) * 16 + tt] = r2 * kscl;                                 \
      ks[(g + 24) * 16 + tt] = r3 * kscl;                                 \
    }                                                                     \
    if (l < 8) {                                                          \
      vs[(4 * m)     * 16 + tt] = c0 * (1.0f / 16.0f);                    \
      vs[(4 * m + 1) * 16 + tt] = c1 * (1.0f / 16.0f);                    \
      vs[(4 * m + 2) * 16 + tt] = c2 * (1.0f / 16.0f);                    \
      vs[(4 * m + 3) * 16 + tt] = c3 * (1.0f / 16.0f);                    \
    }                                                                     \
    if (l == 0) {                                                         \
      const float mean = t1 * (1.0f / 1024.0f);                           \
      bs[tt] = 2.0f * fast_sigmoid(sc * mean + bi);                       \
    }                                                                     \
  } while (0)

#define FLUSH(CH)                                                         \
  do {                                                                    \
    float* rec = recs + ((size_t)bh * NCHUNK + (CH)) * REC_F;             \
    _Pragma("unroll")                                                     \
    for (int rep = 0; rep < 2; ++rep) {                                   \
      const int cc = l + rep * 64;                                        \
      *(float4*)(rec + 4 * cc)       = *(const float4*)&ks[4 * cc];       \
      *(float4*)(rec + 512 + 4 * cc) = *(const float4*)&vs[4 * cc];       \
    }                                                                     \
    if (l < 4) *(float4*)(rec + 1024 + 4 * l) = *(const float4*)&bs[4 * l]; \
    __builtin_amdgcn_fence(__ATOMIC_RELEASE, "agent");                    \
    if (l == 0)                                                           \
      __hip_atomic_store(&flags[bh * NCHUNK + (CH)], 1, __ATOMIC_RELAXED, \
                         __HIP_MEMORY_SCOPE_AGENT);                       \
  } while (0)

    float4 At0, At1, At2, At3, Bt0, Bt1, Bt2, Bt3;
    float4 Ct0, Ct1, Ct2, Ct3, Dt0, Dt1, Dt2, Dt3;
    LOAD_T(A, 0); LOAD_T(B, 1); LOAD_T(C, 2); LOAD_T(D, 3);

    for (int j = 0; j < 32; ++j) {
      const int t0 = 4 * j;
      STAT_TILE(A, t0 & 15);
      if (j < 31) LOAD_T(A, t0 + 4);
      STAT_TILE(B, (t0 + 1) & 15);
      if (j < 31) LOAD_T(B, t0 + 5);
      STAT_TILE(C, (t0 + 2) & 15);
      if (j < 31) LOAD_T(C, t0 + 6);
      STAT_TILE(D, (t0 + 3) & 15);
      if (j < 31) LOAD_T(D, t0 + 7);
      if ((j & 3) == 3) {                       // job boundary: 16 tiles done
        const int ch = (j >> 2) * 8 + c0b;
        FLUSH(ch);
      }
    }
#undef FLUSH
#undef STAT_TILE
#undef LOAD_T
    return;
  }

  // ================================ consumer ================================
  __builtin_amdgcn_s_setprio(3);                 // favor the serial chain
  const int lane = tid & 63;
  const int g    = lane >> 4;                    // group in wave (0..3)
  const int s    = lane & 15;                    // lane in group
  const int w    = blockIdx.x * 4 + (tid >> 6);  // global wave 0..511
  const int bh   = w >> 3;                       // 0..63
  const int i    = (w & 7) * 4 + g;              // 0..31
  const int chain = bh * 32 + i;

  const float2 sini = *(const float2*)(S0 + (size_t)bh * 1024 + i * 32 + 2 * s);
  float Sa = sini.x, Sb = sini.y;

  const float* recb = recs + (size_t)bh * NCHUNK * REC_F;
  const int*   flg  = flags + bh * NCHUNK;
  float* outp = out + chain;

  // per-chunk state in NAMED quads only -> guaranteed register residency
  float4 Ak0q0, Ak0q1, Ak0q2, Ak0q3, Ak1q0, Ak1q1, Ak1q2, Ak1q3;
  float4 Avq0,  Avq1,  Avq2,  Avq3,  Abq0,  Abq1,  Abq2,  Abq3;
  float4 Bk0q0, Bk0q1, Bk0q2, Bk0q3, Bk1q0, Bk1q1, Bk1q2, Bk1q3;
  float4 Bvq0,  Bvq1,  Bvq2,  Bvq3,  Bbq0,  Bbq1,  Bbq2,  Bbq3;

#define FLAG_LD(c) \
  __hip_atomic_load(&flg[(c)], __ATOMIC_RELAXED, __HIP_MEMORY_SCOPE_AGENT)

#define SPIN(fv, c)                                                       \
  do {                                                                    \
    int _f = (fv);                                                        \
    int _n = 0;                                                           \
    while (_f == 0 && _n < SPIN_BOUND) {                                  \
      __builtin_amdgcn_s_sleep(2);                                        \
      _f = FLAG_LD(c);                                                    \
      ++_n;                                                               \
    }                                                                     \
  } while (0)

#define ACQ __builtin_amdgcn_fence(__ATOMIC_ACQUIRE, "agent")

#define LOAD_REC(P, CHK)                                                  \
  do {                                                                    \
    const float* _r  = recb + (size_t)(CHK) * REC_F;                      \
    const float* _k0 = _r + (2 * s) * 16;                                 \
    const float* _k1 = _r + (2 * s + 1) * 16;                             \
    const float* _v  = _r + 512 + i * 16;                                 \
    const float* _b  = _r + 1024;                                         \
    P##k0q0 = *(const float4*)(_k0 + 0);  P##k0q1 = *(const float4*)(_k0 + 4); \
    P##k0q2 = *(const float4*)(_k0 + 8);  P##k0q3 = *(const float4*)(_k0 + 12);\
    P##k1q0 = *(const float4*)(_k1 + 0);  P##k1q1 = *(const float4*)(_k1 + 4); \
    P##k1q2 = *(const float4*)(_k1 + 8);  P##k1q3 = *(const float4*)(_k1 + 12);\
    P##vq0  = *(const float4*)(_v + 0);   P##vq1  = *(const float4*)(_v + 4);  \
    P##vq2  = *(const float4*)(_v + 8);   P##vq3  = *(const float4*)(_v + 12); \
    P##bq0  = *(const float4*)(_b + 0);   P##bq1  = *(const float4*)(_b + 4);  \
    P##bq2  = *(const float4*)(_b + 8);   P##bq3  = *(const float4*)(_b + 12); \
  } while (0)

#define STEP4(P, Q, BASE)                                                       \
  step1(Sa, Sb, P##k0##Q.x, P##k1##Q.x, P##v##Q.x, P##b##Q.x, (BASE) + 0, s, oacc); \
  step1(Sa, Sb, P##k0##Q.y, P##k1##Q.y, P##v##Q.y, P##b##Q.y, (BASE) + 1, s, oacc); \
  step1(Sa, Sb, P##k0##Q.z, P##k1##Q.z, P##v##Q.z, P##b##Q.z, (BASE) + 2, s, oacc); \
  step1(Sa, Sb, P##k0##Q.w, P##k1##Q.w, P##v##Q.w, P##b##Q.w, (BASE) + 3, s, oacc);

#define STEP_CHUNK(P, TBASE)                                              \
  do {                                                                    \
    float oacc = 0.0f;                                                    \
    STEP4(P, q0, 0) STEP4(P, q1, 4) STEP4(P, q2, 8) STEP4(P, q3, 12)      \
    outp[(size_t)((TBASE) + s) * 2048] = oacc;                            \
  } while (0)

  int f0 = FLAG_LD(0);
  SPIN(f0, 0);
  ACQ;
  LOAD_REC(A, 0);                                // chunk 0 (t = 0..15)
  int fB = FLAG_LD(1);

  for (int c0 = 0; c0 < NCHUNK; c0 += 2) {
    const int cB  = c0 + 1;                      // always < NCHUNK
    const int cA2 = (c0 + 2 < NCHUNK) ? c0 + 2 : c0;  // clamp (dead data)
    int fA2 = FLAG_LD(cA2);
    SPIN(fB, cB);
    SPIN(fA2, cA2);
    ACQ;                                         // one fence covers cB + cA2
    LOAD_REC(B, cB);                             // prefetch block B
    STEP_CHUNK(A, c0 * 16);                      // compute block A
    LOAD_REC(A, cA2);                            // prefetch next block A
    fB = FLAG_LD((cB + 2 < NCHUNK) ? cB + 2 : cB);  // probe hidden under B
    STEP_CHUNK(B, cB * 16);                      // compute block B
  }

#undef STEP_CHUNK
#undef STEP4
#undef LOAD_REC
#undef ACQ
#undef SPIN
#undef FLAG_LD

  float2 sfin; sfin.x = Sa; sfin.y = Sb;
  *(float2*)(Sfin + (size_t)bh * 1024 + i * 32 + 2 * s) = sfin;
}

extern "C" void kernel_launch(void* const* d_in, const int* in_sizes, int n_in,
                              void* d_out, int out_size, void* d_ws, size_t ws_size,
                              hipStream_t stream) {
  const float* x     = (const float*)d_in[0];   // [1024, 8, 8192] f32
  const float* S0    = (const float*)d_in[1];   // [8, 8, 32, 32] f32
  const float* scale = (const float*)d_in[2];   // scalar
  const float* bias  = (const float*)d_in[3];   // scalar
  float* out = (float*)d_out;                   // [1024,8,256] then S_final

  float* recs = (float*)d_ws;                   // [4096][1088] f32 (~17.8 MB)
  int* flags  = (int*)(recs + (size_t)NREC * REC_F);  // [4096] i32 (16 KB)

  init_flags<<<16, 256, 0, stream>>>(flags);

  float* Sfin = out + (size_t)T_STEPS * 2048;   // after 2,097,152 output floats
  fused_kernel<<<SCAN_BLOCKS + PROD_BLOCKS, 256, 0, stream>>>(
      x, S0, scale, bias, recs, flags, out, Sfin);
}

// Round 5
// 463.763 us; speedup vs baseline: 1.6492x; 1.3687x over previous
//
#include <hip/hip_runtime.h>
#include <math.h>

// Problem constants: T=1024, B=8, H=8, N=32. D = H*N*N = 8192.
#define T_STEPS 1024
#define NBH     64          // B*H
#define NTILE   65536       // T*B*H

static __device__ __forceinline__ float fast_rcp(float x) {
  return __builtin_amdgcn_rcpf(x);
}
static __device__ __forceinline__ float fast_sigmoid(float x) {
  return fast_rcp(1.0f + __expf(-x));
}
// tanh(x) where y = 2x is passed: tanh = 1 - 2/(1+e^{2x})
static __device__ __forceinline__ float fast_tanh2(float y) {
  return 1.0f - 2.0f * fast_rcp(1.0f + __expf(y));
}

// DPP add: x + lane-permuted(x). CTRL is a compile-time DPP control.
template <int CTRL>
static __device__ __forceinline__ float dpp_add(float x) {
  int y = __builtin_amdgcn_update_dpp(0, __float_as_int(x), CTRL, 0xF, 0xF, true);
  return x + __int_as_float(y);
}

// Butterfly sum over each 16-lane group; result in all 16 lanes. Pure DPP.
static __device__ __forceinline__ float red16(float x) {
  x = dpp_add<0xB1>(x);    // quad_perm(1,0,3,2)  == xor 1
  x = dpp_add<0x4E>(x);    // quad_perm(2,3,0,1)  == xor 2
  x = dpp_add<0x141>(x);   // row_half_mirror     == xor 4
  x = dpp_add<0x140>(x);   // row_mirror          == xor 8
  return x;
}

// ---------------------------------------------------------------------------
// Phase A: per-(t,b,h) tile statistics. One wave handles 16 consecutive t of
// one bh (4096 jobs). Per-tile reductions identical to verified R2/R3 code.
// Results staged in LDS [elem][16], flushed with coalesced dwordx4 stores to
// t-major layout: knT2[bh][elem][t], vvT2[bh][elem][t] (=2*v), bbT2[bh][t]
// (=2*beta).
// ---------------------------------------------------------------------------
__global__ __launch_bounds__(256) void stats_kernel(
    const float* __restrict__ x, const float* __restrict__ scale_p,
    const float* __restrict__ bias_p, float* __restrict__ knT2,
    float* __restrict__ vvT2, float* __restrict__ bbT2) {
  const int tid = threadIdx.x;
  const int l   = tid & 63;
  const int m   = l & 7;
  const int g   = l >> 3;
  const int wib = tid >> 6;                 // wave in block 0..3
  const int job = blockIdx.x * 4 + wib;     // 0..4095
  const int bh  = job >> 6;
  const int t0  = (job & 63) << 4;          // chunk of 16 t
  const float sc = scale_p[0], bi = bias_p[0];

  __shared__ float kn_s[4][512];            // [wave][elem*16 + tt]
  __shared__ float vv_s[4][512];
  __shared__ float bb_s[4][16];
  float* ks = kn_s[wib];
  float* vs = vv_s[wib];
  float* bs = bb_s[wib];

  // tile tt lives at x + ((t0+tt)*64 + bh)*1024 ; stride between tt = 65536
  const float4* xp = (const float4*)(x + ((size_t)t0 * 64 + bh) * 1024);
  // preload tile 0
  float4 a0 = xp[l], a1 = xp[l + 64], a2 = xp[l + 128], a3 = xp[l + 192];

  for (int tt = 0; tt < 16; ++tt) {
    float4 b0, b1, b2, b3;
    if (tt < 15) {
      const float4* xn = xp + (size_t)(tt + 1) * 16384;  // +64*1024 floats
      b0 = xn[l]; b1 = xn[l + 64]; b2 = xn[l + 128]; b3 = xn[l + 192];
    }

    // row partials; reduce over m: xor 1,2,4
    float r0 = (a0.x + a0.y) + (a0.z + a0.w);
    float r1 = (a1.x + a1.y) + (a1.z + a1.w);
    float r2 = (a2.x + a2.y) + (a2.z + a2.w);
    float r3 = (a3.x + a3.y) + (a3.z + a3.w);
    r0 += __shfl_xor(r0, 1); r1 += __shfl_xor(r1, 1);
    r2 += __shfl_xor(r2, 1); r3 += __shfl_xor(r3, 1);
    r0 += __shfl_xor(r0, 2); r1 += __shfl_xor(r1, 2);
    r2 += __shfl_xor(r2, 2); r3 += __shfl_xor(r3, 2);
    r0 += __shfl_xor(r0, 4); r1 += __shfl_xor(r1, 4);
    r2 += __shfl_xor(r2, 4); r3 += __shfl_xor(r3, 4);
    // r0..r3 = row sums for rows g, g+8, g+16, g+24 (all lanes)

    // col partials; reduce over g: xor 8,16,32
    float c0 = a0.x + a1.x + a2.x + a3.x;
    float c1 = a0.y + a1.y + a2.y + a3.y;
    float c2 = a0.z + a1.z + a2.z + a3.z;
    float c3 = a0.w + a1.w + a2.w + a3.w;
    c0 += __shfl_xor(c0, 8);  c1 += __shfl_xor(c1, 8);
    c2 += __shfl_xor(c2, 8);  c3 += __shfl_xor(c3, 8);
    c0 += __shfl_xor(c0, 16); c1 += __shfl_xor(c1, 16);
    c2 += __shfl_xor(c2, 16); c3 += __shfl_xor(c3, 16);
    c0 += __shfl_xor(c0, 32); c1 += __shfl_xor(c1, 32);
    c2 += __shfl_xor(c2, 32); c3 += __shfl_xor(c3, 32);
    // c0..c3 = col sums for cols 4m..4m+3 (all lanes)

    // sum(k), ||k||^2 over rows; reduce over g
    float t1 = (r0 + r1) + (r2 + r3);
    float t2 = (r0 * r0 + r1 * r1) + (r2 * r2 + r3 * r3);
    t1 += __shfl_xor(t1, 8);  t2 += __shfl_xor(t2, 8);
    t1 += __shfl_xor(t1, 16); t2 += __shfl_xor(t2, 16);
    t1 += __shfl_xor(t1, 32); t2 += __shfl_xor(t2, 32);
    const float norm = sqrtf(t2) * (1.0f / 32.0f);   // ||k||, k = rowsum/32
    const float kscl = (1.0f / 32.0f) * fast_rcp(norm + 1e-6f);

    if (m == 0) {          // 8 lanes: knorm elements g+8p for this tt
      ks[(g)      * 16 + tt] = r0 * kscl;
      ks[(g + 8)  * 16 + tt] = r1 * kscl;
      ks[(g + 16) * 16 + tt] = r2 * kscl;
      ks[(g + 24) * 16 + tt] = r3 * kscl;
    }
    if (l < 8) {           // lanes 0..7 (m==l): V2 = 2*colmean = colsum/16
      vs[(4 * m)     * 16 + tt] = c0 * (1.0f / 16.0f);
      vs[(4 * m + 1) * 16 + tt] = c1 * (1.0f / 16.0f);
      vs[(4 * m + 2) * 16 + tt] = c2 * (1.0f / 16.0f);
      vs[(4 * m + 3) * 16 + tt] = c3 * (1.0f / 16.0f);
    }
    if (l == 0) {          // B2 = 2*beta
      const float mean = t1 * (1.0f / 1024.0f);
      bs[tt] = 2.0f * fast_sigmoid(sc * mean + bi);
    }

    a0 = b0; a1 = b1; a2 = b2; a3 = b3;
  }

  // flush (same wave wrote the LDS; lgkmcnt ordering only, no barrier needed)
  const size_t rowbase = (size_t)bh * 32 * T_STEPS + t0;
#pragma unroll
  for (int rep = 0; rep < 2; ++rep) {
    const int c = l + rep * 64;       // chunk 0..127
    const int e = c >> 2;             // elem 0..31
    const int q = c & 3;              // quarter of the 16-t run
    const float4 kv = *(const float4*)&ks[e * 16 + q * 4];
    const float4 vv = *(const float4*)&vs[e * 16 + q * 4];
    *(float4*)(knT2 + rowbase + (size_t)e * T_STEPS + q * 4) = kv;
    *(float4*)(vvT2 + rowbase + (size_t)e * T_STEPS + q * 4) = vv;
  }
  if (l < 4) {
    const float4 bv = *(const float4*)&bs[l * 4];
    *(float4*)(bbT2 + (size_t)bh * T_STEPS + t0 + l * 4) = bv;
  }
}

// ---------------------------------------------------------------------------
// Phase B: serial scan. 2048 chains (bh,i); 16 lanes per chain, lane owns
// cols {2s, 2s+1}. Reduction = 4 pure-DPP adds. Stats streamed t-major with
// 16-step double buffering. vv holds V2=2v, bb holds B2=2*beta so the tanh
// argument is B2*S + (V2-2r)*kn with no extra doubling on the serial chain.
// ---------------------------------------------------------------------------
__global__ __launch_bounds__(256, 1) void scan_kernel(
    const float* __restrict__ S0, const float* __restrict__ knT2,
    const float* __restrict__ vvT2, const float* __restrict__ bbT2,
    float* __restrict__ out, float* __restrict__ Sfin) {
  const int tid  = threadIdx.x;
  const int lane = tid & 63;
  const int g    = lane >> 4;                    // group in wave (0..3)
  const int s    = lane & 15;                    // lane in group
  const int w    = blockIdx.x * 4 + (tid >> 6);  // global wave 0..511
  const int bh   = w >> 3;                       // 0..63
  const int i    = (w & 7) * 4 + g;              // 0..31
  const int chain = bh * 32 + i;

  const float2 sini = *(const float2*)(S0 + (size_t)bh * 1024 + i * 32 + 2 * s);
  float Sa = sini.x, Sb = sini.y;

  const float* kn0p = knT2 + ((size_t)bh * 32 + 2 * s) * T_STEPS;
  const float* kn1p = kn0p + T_STEPS;
  const float* vp   = vvT2 + ((size_t)bh * 32 + i) * T_STEPS;
  const float* bp   = bbT2 + (size_t)bh * T_STEPS;

  float Ak0[16], Ak1[16], Av[16], Ab[16];
  float Bk0[16], Bk1[16], Bv[16], Bb[16];

#define LOAD_BLK(K0, K1, VV, BE, TOFF)                                    \
  do {                                                                    \
    const int _to = (TOFF);                                               \
    _Pragma("unroll")                                                     \
    for (int qq = 0; qq < 4; ++qq) {                                      \
      *(float4*)&K0[4 * qq] = *(const float4*)(kn0p + _to + 4 * qq);      \
      *(float4*)&K1[4 * qq] = *(const float4*)(kn1p + _to + 4 * qq);      \
      *(float4*)&VV[4 * qq] = *(const float4*)(vp   + _to + 4 * qq);      \
      *(float4*)&BE[4 * qq] = *(const float4*)(bp   + _to + 4 * qq);      \
    }                                                                     \
  } while (0)

#define STEP_BLK(K0, K1, VV, BE, TBASE)                                   \
  do {                                                                    \
    float oacc = 0.0f;                                                    \
    _Pragma("unroll")                                                     \
    for (int u = 0; u < 16; ++u) {                                        \
      const float c0 = K0[u], c1 = K1[u];                                 \
      const float r  = red16(Sa * c0 + Sb * c1);                          \
      const float D2 = fmaf(-2.0f, r, VV[u]);   /* 2*(v - r) */           \
      const float B2 = BE[u];                                             \
      Sa = fast_tanh2(fmaf(B2, Sa, D2 * c0));                             \
      Sb = fast_tanh2(fmaf(B2, Sb, D2 * c1));                             \
      const float qv = red16(Sa * c0 + Sb * c1);                          \
      const float o  = qv * qv * fast_sigmoid(qv);                        \
      oacc = (u == s) ? o : oacc;                                         \
    }                                                                     \
    outp[(size_t)((TBASE) + s) * 2048] = oacc;                            \
  } while (0)

  float* outp = out + chain;

  LOAD_BLK(Ak0, Ak1, Av, Ab, 0);                 // t = 0..15

  for (int t0 = 0; t0 < T_STEPS; t0 += 32) {
    const int tB = t0 + 16;                      // always < T_STEPS
    const int tA2 = (t0 + 32 < T_STEPS) ? t0 + 32 : t0;  // clamp (dead data)
    LOAD_BLK(Bk0, Bk1, Bv, Bb, tB);              // prefetch block B
    STEP_BLK(Ak0, Ak1, Av, Ab, t0);              // compute block A
    LOAD_BLK(Ak0, Ak1, Av, Ab, tA2);             // prefetch next block A
    STEP_BLK(Bk0, Bk1, Bv, Bb, tB);              // compute block B
  }

#undef LOAD_BLK
#undef STEP_BLK

  float2 sfin; sfin.x = Sa; sfin.y = Sb;
  *(float2*)(Sfin + (size_t)bh * 1024 + i * 32 + 2 * s) = sfin;
}

extern "C" void kernel_launch(void* const* d_in, const int* in_sizes, int n_in,
                              void* d_out, int out_size, void* d_ws, size_t ws_size,
                              hipStream_t stream) {
  const float* x     = (const float*)d_in[0];   // [1024, 8, 8192] f32
  const float* S0    = (const float*)d_in[1];   // [8, 8, 32, 32] f32
  const float* scale = (const float*)d_in[2];   // scalar
  const float* bias  = (const float*)d_in[3];   // scalar
  float* out = (float*)d_out;                   // [1024,8,256] then S_final

  float* knT2 = (float*)d_ws;                   // [64][32][1024]
  float* vvT2 = knT2 + (size_t)NTILE * 32;      // [64][32][1024]  (2*v)
  float* bbT2 = vvT2 + (size_t)NTILE * 32;      // [64][1024]      (2*beta)
  // total ws use: ~16.3 MB

  stats_kernel<<<1024, 256, 0, stream>>>(x, scale, bias, knT2, vvT2, bbT2);

  float* Sfin = out + (size_t)T_STEPS * 2048;   // after 2,097,152 output floats
  scan_kernel<<<128, 256, 0, stream>>>(S0, knT2, vvT2, bbT2, out, Sfin);
}